// Round 1
// 567.088 us; speedup vs baseline: 1.0079x; 1.0079x over previous
//
#include <hip/hip_runtime.h>

// CombineUV: out[b,s] = <input[b,:]*sig(alpha), W[l,:]> + <input[b,:]*sig(beta), V[l,:]> + bias[l]
// with l = shortlist[b,s]. L=131072, D=512, B=512, S=512.
// Memory-bound on the ~0.5 GB unique-row gather (453 MB compulsory floor, measured 536 MB).
//
// R2 restructure: latency-bound fix.
//  - 16-lane groups: each group owns one s-value; a wave processes 4 s-values
//    per iteration -> 16 float4 loads in flight (16 KB/wave/iter, 2x previous).
//  - Reduction: 4 __shfl_xor (8/4/2/1) reduce ALL 4 s-values at once
//    (vs 24 shuffles for 4 s-values before; chain depth 6 -> 4).
//  - bias pre-gathered to LDS at block start: no dependent scalar load on the
//    store path.
//  - Gate fragments (ga/gb) read per-iteration from LDS as float4: broadcast
//    across the 4 groups, 2-way (free) within a group.
// NOTE: harness delivers shortlist as int32 (reading int64 faulted in R1).

#define D_DIM 512
#define S_DIM 512

__global__ __launch_bounds__(256, 4)
void combine_uv_kernel(
    const float* __restrict__ input,     // [B, D]
    const float* __restrict__ labels,    // [L, D]  'v'
    const float* __restrict__ weight,    // [L, D]  'u'
    const float* __restrict__ alpha,     // [1, D]
    const float* __restrict__ beta,      // [1, D]
    const float* __restrict__ bias,      // [L]
    const int* __restrict__ shortlist,   // [B, S] (int32 on device)
    float* __restrict__ out)             // [B, S]
{
    __shared__ float ga[D_DIM];   // input[b,:] * sigmoid(alpha)
    __shared__ float gb[D_DIM];   // input[b,:] * sigmoid(beta)
    __shared__ int   sl[64];      // this block's shortlist slice
    __shared__ float bb[64];      // pre-gathered bias for the slice

    const int b   = blockIdx.x;
    const int s0  = blockIdx.y * 64;
    const int tid = threadIdx.x;

    // Stage gated input row into LDS (512 exp per block, trivial).
    for (int d = tid; d < D_DIM; d += 256) {
        float x  = input[b * D_DIM + d];
        float sa = 1.0f / (1.0f + __expf(-alpha[d]));
        float sb = 1.0f / (1.0f + __expf(-beta[d]));
        ga[d] = x * sa;
        gb[d] = x * sb;
    }
    if (tid < 64) {
        const int l = shortlist[b * S_DIM + s0 + tid];
        sl[tid] = l;
        bb[tid] = bias[l];     // one-time uncoalesced 4B gather, off the hot path
    }
    __syncthreads();

    const int wave = tid >> 6;    // 0..3
    const int lane = tid & 63;
    const int g    = lane >> 4;   // 16-lane group -> one s-value
    const int m    = lane & 15;   // position within group

    const float4* gaf = (const float4*)ga;
    const float4* gbf = (const float4*)gb;

    // Each wave: 16 s-values, 4 per iteration (one per group).
    #pragma unroll
    for (int i = 0; i < 4; ++i) {
        const int    si = wave * 16 + i * 4 + g;
        const size_t l  = (size_t)sl[si];            // broadcast within group
        const float4* wrow = (const float4*)(weight + l * D_DIM);
        const float4* vrow = (const float4*)(labels + l * D_DIM);

        // 16 coalesced 16B loads in flight per lane-group-iteration.
        // Group reads 256B contiguous per k-step (16 lanes x 16B).
        float4 wd[8], vd[8];
        #pragma unroll
        for (int k = 0; k < 8; ++k) wd[k] = wrow[m + 16 * k];
        #pragma unroll
        for (int k = 0; k < 8; ++k) vd[k] = vrow[m + 16 * k];

        float acc = 0.0f;
        #pragma unroll
        for (int k = 0; k < 8; ++k) {
            const float4 a = gaf[m + 16 * k];        // LDS broadcast across groups
            acc += wd[k].x * a.x + wd[k].y * a.y + wd[k].z * a.z + wd[k].w * a.w;
        }
        #pragma unroll
        for (int k = 0; k < 8; ++k) {
            const float4 c = gbf[m + 16 * k];
            acc += vd[k].x * c.x + vd[k].y * c.y + vd[k].z * c.z + vd[k].w * c.w;
        }

        // One 4-step butterfly reduces all 4 groups' s-values simultaneously.
        acc += __shfl_xor(acc, 8, 64);
        acc += __shfl_xor(acc, 4, 64);
        acc += __shfl_xor(acc, 2, 64);
        acc += __shfl_xor(acc, 1, 64);

        if (m == 0) out[b * S_DIM + s0 + si] = acc + bb[si];
    }
}

extern "C" void kernel_launch(void* const* d_in, const int* in_sizes, int n_in,
                              void* d_out, int out_size, void* d_ws, size_t ws_size,
                              hipStream_t stream) {
    const float* input     = (const float*)d_in[0];
    const float* labels    = (const float*)d_in[1];
    const float* weight    = (const float*)d_in[2];
    const float* alpha     = (const float*)d_in[3];
    const float* beta      = (const float*)d_in[4];
    const float* bias      = (const float*)d_in[5];
    const int* shortlist   = (const int*)d_in[6];
    float* out             = (float*)d_out;

    const int B = 512;
    const int S = 512;
    dim3 grid(B, S / 64);   // 4096 blocks
    dim3 block(256);
    combine_uv_kernel<<<grid, block, 0, stream>>>(
        input, labels, weight, alpha, beta, bias, shortlist, out);
}